// Round 7
// baseline (653.114 us; speedup 1.0000x reference)
//
#include <hip/hip_runtime.h>

// Problem constants
#define BB 8192
#define CC 4096
#define GG 16
#define SS 256
#define RR 512
#define NN (GG*RR)   // 8192 output cols

typedef __bf16 bf16x8 __attribute__((ext_vector_type(8)));
typedef float  f32x4_t __attribute__((ext_vector_type(4)));

__device__ __forceinline__ void gld_lds16(const void* g, void* l){
  __builtin_amdgcn_global_load_lds((const __attribute__((address_space(1))) void*)g,
                                   (__attribute__((address_space(3))) void*)l, 16, 0, 0);
}

// ---------------- Pass 1: fused {per-row gather+cast} and {W cast} ----------
// Blocks 0..BB-1: permute+cast one x row (16KB LDS, 8 blk/CU).
// Blocks BB..BB+1023: cast one W chunk. Native bf16 casts (v_cvt_pk_bf16_f32).
__global__ void __launch_bounds__(256) prep_kernel(
    const float* __restrict__ x, const int* __restrict__ perm,
    const float* __restrict__ W,
    unsigned short* __restrict__ xp, unsigned short* __restrict__ Wb)
{
  __shared__ float row[CC];
  const int tid = threadIdx.x;
  const int bid = blockIdx.x;
  if (bid < BB) {
    const size_t b = bid;
    const float4* xr = (const float4*)(x + b*CC);
    float4* rr = (float4*)row;
    #pragma unroll
    for (int c=0;c<4;++c) rr[c*256+tid] = xr[c*256+tid];
    __syncthreads();
    unsigned short* xo = xp + b*CC;
    #pragma unroll
    for (int c=0;c<2;++c){
      const int j0 = (((c<<8)+tid)<<3);
      const int4 p0 = *(const int4*)(perm + j0);
      const int4 p1 = *(const int4*)(perm + j0 + 4);
      bf16x8 v;
      v[0]=(__bf16)row[p0.x]; v[1]=(__bf16)row[p0.y];
      v[2]=(__bf16)row[p0.z]; v[3]=(__bf16)row[p0.w];
      v[4]=(__bf16)row[p1.x]; v[5]=(__bf16)row[p1.y];
      v[6]=(__bf16)row[p1.z]; v[7]=(__bf16)row[p1.w];
      *(bf16x8*)(xo + j0) = v;
    }
  } else {
    const int i = (((bid - BB)<<8) + tid)<<3;
    const float4 f0 = ((const float4*)(W+i))[0];
    const float4 f1 = ((const float4*)(W+i))[1];
    bf16x8 v;
    v[0]=(__bf16)f0.x; v[1]=(__bf16)f0.y; v[2]=(__bf16)f0.z; v[3]=(__bf16)f0.w;
    v[4]=(__bf16)f1.x; v[5]=(__bf16)f1.y; v[6]=(__bf16)f1.z; v[7]=(__bf16)f1.w;
    *(bf16x8*)(Wb+i) = v;
  }
}

// ---------------- Pass 2: grouped GEMM, BM=128 x BN=512 (whole group) -------
// Each block owns one (group g, 128-row stripe): A-slice fetched EXACTLY once
// (structural reuse, not L2-dependent). B 512x64 staged per K-step; per-XCD
// B working set 512 KB -> L2-resident. 8 waves (2x4), per-wave 64x128 out,
// single-buffered 80 KB LDS -> 2 blocks/CU. T2 swizzle both-sides, T1 map.
__global__ void __launch_bounds__(512, 4) gemm_kernel(
    const unsigned short* __restrict__ xp, const unsigned short* __restrict__ Wb,
    const float* __restrict__ bias, float* __restrict__ out)
{
  __shared__ unsigned short lA[128*64];   // 16 KB
  __shared__ unsigned short lB[512*64];   // 64 KB
  const int tid  = threadIdx.x;
  const int lane = tid & 63;
  const int w    = tid >> 6;
  const int wr   = w >> 2;          // 0..1  (64 out rows)
  const int wc   = w & 3;           // 0..3  (128 out cols)
  const int l15  = lane & 15, lh = lane >> 4;

  // XCD map: 1024 blocks; xcd owns groups {2*xcd, 2*xcd+1}; by streams.
  const int bid   = blockIdx.x;
  const int xcd   = bid & 7;
  const int local = bid >> 3;                   // 0..127
  const int g     = (xcd << 1) | (local & 1);   // 0..15
  const int by    = local >> 1;                 // 0..63

  const int m0 = by << 7;
  const size_t arow0 = (size_t)m0*CC + (size_t)g*SS;
  const size_t brow0 = (size_t)g*RR*SS;

  f32x4_t acc[4][8];
  #pragma unroll
  for (int i=0;i<4;++i)
    #pragma unroll
    for (int j=0;j<8;++j)
      acc[i][j] = (f32x4_t){0.f,0.f,0.f,0.f};

  #pragma unroll
  for (int t=0;t<4;++t){
    const int kk = t<<6;
    // STAGE A: 128x64 bf16 = 1024 chunks (2/thread), swizzled source (T2).
    #pragma unroll
    for (int c=0;c<2;++c){
      const int i  = (c<<9) + tid;           // 0..1023
      const int r  = i>>3;                   // 0..127
      const int cs = ((i&7) ^ (r&7)) << 3;
      gld_lds16(xp + arow0 + (size_t)r*CC + kk + cs, &lA[i<<3]);
    }
    // STAGE B: 512x64 bf16 = 4096 chunks (8/thread).
    #pragma unroll
    for (int c=0;c<8;++c){
      const int i  = (c<<9) + tid;           // 0..4095
      const int r  = i>>3;                   // 0..511 (n within group)
      const int cs = ((i&7) ^ (r&7)) << 3;
      gld_lds16(Wb + brow0 + (size_t)r*SS + kk + cs, &lB[i<<3]);
    }
    __syncthreads();                         // compiler emits vmcnt(0) drain
    #pragma unroll
    for (int ks=0;ks<2;++ks){
      bf16x8 af[4], bfr[8];
      const int cc = (ks<<2) + lh;           // logical 16B chunk col 0..7
      #pragma unroll
      for (int mi=0;mi<4;++mi){
        const int ar = (wr<<6)+(mi<<4)+l15;
        af[mi]  = *(const bf16x8*)&lA[ar*64 + ((cc ^ (ar&7))<<3)];
      }
      #pragma unroll
      for (int ni=0;ni<8;++ni){
        const int br = (wc<<7)+(ni<<4)+l15;
        bfr[ni] = *(const bf16x8*)&lB[br*64 + ((cc ^ (br&7))<<3)];
      }
      #pragma unroll
      for (int mi=0;mi<4;++mi)
        #pragma unroll
        for (int ni=0;ni<8;++ni)
          acc[mi][ni] = __builtin_amdgcn_mfma_f32_16x16x32_bf16(af[mi], bfr[ni], acc[mi][ni], 0,0,0);
    }
    __syncthreads();                         // all reads done before next STAGE
  }

  // Epilogue: bias add + store. D layout: col=lane&15, row=(lane>>4)*4+reg.
  #pragma unroll
  for (int ni=0;ni<8;++ni){
    const int col = (g<<9) + (wc<<7) + (ni<<4) + l15;
    const float bv = bias[col];
    #pragma unroll
    for (int mi=0;mi<4;++mi){
      const int rb = m0 + (wr<<6) + (mi<<4) + (lh<<2);
      float* op = out + (size_t)rb*NN + col;
      #pragma unroll
      for (int r=0;r<4;++r)
        op[(size_t)r*NN] = acc[mi][ni][r] + bv;
    }
  }
}

extern "C" void kernel_launch(void* const* d_in, const int* in_sizes, int n_in,
                              void* d_out, int out_size, void* d_ws, size_t ws_size,
                              hipStream_t stream) {
  const float* x    = (const float*)d_in[0];   // [B, C] f32
  const float* W    = (const float*)d_in[1];   // [G, R, S] f32
  const float* bias = (const float*)d_in[2];   // [G, R] f32
  const int*   perm = (const int*)d_in[3];     // [G, S] int32
  float* out = (float*)d_out;                  // [B, G*R] f32

  unsigned short* xp = (unsigned short*)d_ws;                            // B*C bf16 = 64 MiB
  unsigned short* Wb = (unsigned short*)((char*)d_ws + (size_t)BB*CC*2); // G*R*S bf16 = 4 MiB

  const int wblocks = (GG*RR*SS)/(256*8);      // 1024
  prep_kernel<<<dim3(BB + wblocks), dim3(256), 0, stream>>>(x, perm, W, xp, Wb);
  gemm_kernel<<<dim3(1024), dim3(512), 0, stream>>>(xp, Wb, bias, out);
}

// Round 8
// 162.932 us; speedup vs baseline: 4.0085x; 4.0085x over previous
//
#include <hip/hip_runtime.h>

// Problem constants
#define BB 8192
#define CC 4096
#define GG 16
#define SS 256
#define RR 512
#define NN (GG*RR)   // 8192 output cols

typedef __bf16 bf16x8 __attribute__((ext_vector_type(8)));
typedef float  f32x4_t __attribute__((ext_vector_type(4)));

__device__ __forceinline__ void gld_lds16(const void* g, void* l){
  __builtin_amdgcn_global_load_lds((const __attribute__((address_space(1))) void*)g,
                                   (__attribute__((address_space(3))) void*)l, 16, 0, 0);
}

// ---------------- Pass 1: fused {per-row gather+cast} and {W cast} ----------
// Blocks 0..BB-1: permute+cast one x row (16KB LDS, 8 blk/CU).
// Blocks BB..BB+1023: cast one W chunk. Native bf16 casts (v_cvt_pk_bf16_f32).
__global__ void __launch_bounds__(256) prep_kernel(
    const float* __restrict__ x, const int* __restrict__ perm,
    const float* __restrict__ W,
    unsigned short* __restrict__ xp, unsigned short* __restrict__ Wb)
{
  __shared__ float row[CC];
  const int tid = threadIdx.x;
  const int bid = blockIdx.x;
  if (bid < BB) {
    const size_t b = bid;
    const float4* xr = (const float4*)(x + b*CC);
    float4* rr = (float4*)row;
    #pragma unroll
    for (int c=0;c<4;++c) rr[c*256+tid] = xr[c*256+tid];
    __syncthreads();
    unsigned short* xo = xp + b*CC;
    #pragma unroll
    for (int c=0;c<2;++c){
      const int j0 = (((c<<8)+tid)<<3);
      const int4 p0 = *(const int4*)(perm + j0);
      const int4 p1 = *(const int4*)(perm + j0 + 4);
      bf16x8 v;
      v[0]=(__bf16)row[p0.x]; v[1]=(__bf16)row[p0.y];
      v[2]=(__bf16)row[p0.z]; v[3]=(__bf16)row[p0.w];
      v[4]=(__bf16)row[p1.x]; v[5]=(__bf16)row[p1.y];
      v[6]=(__bf16)row[p1.z]; v[7]=(__bf16)row[p1.w];
      *(bf16x8*)(xo + j0) = v;
    }
  } else {
    const int i = (((bid - BB)<<8) + tid)<<3;
    const float4 f0 = ((const float4*)(W+i))[0];
    const float4 f1 = ((const float4*)(W+i))[1];
    bf16x8 v;
    v[0]=(__bf16)f0.x; v[1]=(__bf16)f0.y; v[2]=(__bf16)f0.z; v[3]=(__bf16)f0.w;
    v[4]=(__bf16)f1.x; v[5]=(__bf16)f1.y; v[6]=(__bf16)f1.z; v[7]=(__bf16)f1.w;
    *(bf16x8*)(Wb+i) = v;
  }
}

// ---------------- Pass 2: grouped GEMM, BM=128 x BN=256 (half group) --------
// 8 waves (2x4), per-wave 64x64 out -> acc[4][4]=64 VGPR (+32 frags, ~116
// total, fits the (512,4) 128-VGPR cap -> NO SPILL, unlike R7's acc[4][8]).
// LDS 48 KB single-buf -> 2 blocks/CU. The two n-halves of each (g, stripe)
// are ADJACENT blocks on the same XCD -> 2nd block's A-fetch L2-hits.
// Per-XCD B working set = 2 groups x 256 KB = 512 KB (L2-resident).
__global__ void __launch_bounds__(512, 4) gemm_kernel(
    const unsigned short* __restrict__ xp, const unsigned short* __restrict__ Wb,
    const float* __restrict__ bias, float* __restrict__ out)
{
  __shared__ unsigned short lA[128*64];   // 16 KB
  __shared__ unsigned short lB[256*64];   // 32 KB
  const int tid  = threadIdx.x;
  const int lane = tid & 63;
  const int w    = tid >> 6;
  const int wr   = w >> 2;          // 0..1  (64 out rows)
  const int wc   = w & 3;           // 0..3  (64 out cols each)
  const int l15  = lane & 15, lh = lane >> 4;

  // XCD map: 2048 blocks, 256/XCD. local: bit0 = n-half (adjacent pair same
  // g/stripe -> A L2 reuse), bit1 = which of this XCD's 2 groups, rest = stripe.
  const int bid   = blockIdx.x;
  const int xcd   = bid & 7;
  const int local = bid >> 3;                   // 0..255
  const int nh    = local & 1;                  // n-half 0/1
  const int g     = (xcd << 1) | ((local >> 1) & 1);
  const int by    = local >> 2;                 // 0..63

  const int m0 = by << 7;
  const int n0 = (g << 9) + (nh << 8);
  const size_t arow0 = (size_t)m0*CC + (size_t)g*SS;
  const size_t brow0 = (size_t)g*RR*SS + (size_t)(nh<<8)*SS;

  f32x4_t acc[4][4];
  #pragma unroll
  for (int i=0;i<4;++i)
    #pragma unroll
    for (int j=0;j<4;++j)
      acc[i][j] = (f32x4_t){0.f,0.f,0.f,0.f};

  #pragma unroll
  for (int t=0;t<4;++t){
    const int kk = t<<6;
    // STAGE A: 128x64 bf16 = 1024 chunks (2/thread), swizzled source (T2).
    #pragma unroll
    for (int c=0;c<2;++c){
      const int i  = (c<<9) + tid;           // 0..1023
      const int r  = i>>3;                   // 0..127
      const int cs = ((i&7) ^ (r&7)) << 3;
      gld_lds16(xp + arow0 + (size_t)r*CC + kk + cs, &lA[i<<3]);
    }
    // STAGE B: 256x64 bf16 = 2048 chunks (4/thread).
    #pragma unroll
    for (int c=0;c<4;++c){
      const int i  = (c<<9) + tid;           // 0..2047
      const int r  = i>>3;                   // 0..255 (n within half-group)
      const int cs = ((i&7) ^ (r&7)) << 3;
      gld_lds16(Wb + brow0 + (size_t)r*SS + kk + cs, &lB[i<<3]);
    }
    __syncthreads();                         // compiler emits vmcnt(0) drain
    #pragma unroll
    for (int ks=0;ks<2;++ks){
      bf16x8 af[4], bfr[4];
      const int cc = (ks<<2) + lh;           // logical 16B chunk col 0..7
      #pragma unroll
      for (int mi=0;mi<4;++mi){
        const int ar = (wr<<6)+(mi<<4)+l15;
        af[mi]  = *(const bf16x8*)&lA[ar*64 + ((cc ^ (ar&7))<<3)];
      }
      #pragma unroll
      for (int ni=0;ni<4;++ni){
        const int br = (wc<<6)+(ni<<4)+l15;
        bfr[ni] = *(const bf16x8*)&lB[br*64 + ((cc ^ (br&7))<<3)];
      }
      #pragma unroll
      for (int mi=0;mi<4;++mi)
        #pragma unroll
        for (int ni=0;ni<4;++ni)
          acc[mi][ni] = __builtin_amdgcn_mfma_f32_16x16x32_bf16(af[mi], bfr[ni], acc[mi][ni], 0,0,0);
    }
    __syncthreads();                         // all reads done before next STAGE
  }

  // Epilogue: bias add + store. D layout: col=lane&15, row=(lane>>4)*4+reg.
  #pragma unroll
  for (int ni=0;ni<4;++ni){
    const int col = n0 + (wc<<6) + (ni<<4) + l15;
    const float bv = bias[col];
    #pragma unroll
    for (int mi=0;mi<4;++mi){
      const int rb = m0 + (wr<<6) + (mi<<4) + (lh<<2);
      float* op = out + (size_t)rb*NN + col;
      #pragma unroll
      for (int r=0;r<4;++r)
        op[(size_t)r*NN] = acc[mi][ni][r] + bv;
    }
  }
}

extern "C" void kernel_launch(void* const* d_in, const int* in_sizes, int n_in,
                              void* d_out, int out_size, void* d_ws, size_t ws_size,
                              hipStream_t stream) {
  const float* x    = (const float*)d_in[0];   // [B, C] f32
  const float* W    = (const float*)d_in[1];   // [G, R, S] f32
  const float* bias = (const float*)d_in[2];   // [G, R] f32
  const int*   perm = (const int*)d_in[3];     // [G, S] int32
  float* out = (float*)d_out;                  // [B, G*R] f32

  unsigned short* xp = (unsigned short*)d_ws;                            // B*C bf16 = 64 MiB
  unsigned short* Wb = (unsigned short*)((char*)d_ws + (size_t)BB*CC*2); // G*R*S bf16 = 4 MiB

  const int wblocks = (GG*RR*SS)/(256*8);      // 1024
  prep_kernel<<<dim3(BB + wblocks), dim3(256), 0, stream>>>(x, perm, W, xp, Wb);
  gemm_kernel<<<dim3(2048), dim3(512), 0, stream>>>(xp, Wb, bias, out);
}

// Round 9
// 133.539 us; speedup vs baseline: 4.8908x; 1.2201x over previous
//
#include <hip/hip_runtime.h>

// Problem constants
#define BB 8192
#define CC 4096
#define GG 16
#define SS 256
#define RR 512
#define NN (GG*RR)   // 8192 output cols

typedef __bf16 bf16x8 __attribute__((ext_vector_type(8)));
typedef float  f32x4_t __attribute__((ext_vector_type(4)));

__device__ __forceinline__ void gld_lds16(const void* g, void* l){
  __builtin_amdgcn_global_load_lds((const __attribute__((address_space(1))) void*)g,
                                   (__attribute__((address_space(3))) void*)l, 16, 0, 0);
}

// ---------------- Pass 1: fused {per-row gather+cast} and {W cast} ----------
// Blocks 0..BB-1: permute+cast one x row (16KB LDS, 8 blk/CU).
// Blocks BB..BB+1023: cast one W chunk. Native bf16 casts (v_cvt_pk_bf16_f32).
__global__ void __launch_bounds__(256) prep_kernel(
    const float* __restrict__ x, const int* __restrict__ perm,
    const float* __restrict__ W,
    unsigned short* __restrict__ xp, unsigned short* __restrict__ Wb)
{
  __shared__ float row[CC];
  const int tid = threadIdx.x;
  const int bid = blockIdx.x;
  if (bid < BB) {
    const size_t b = bid;
    const float4* xr = (const float4*)(x + b*CC);
    float4* rr = (float4*)row;
    #pragma unroll
    for (int c=0;c<4;++c) rr[c*256+tid] = xr[c*256+tid];
    __syncthreads();
    unsigned short* xo = xp + b*CC;
    #pragma unroll
    for (int c=0;c<2;++c){
      const int j0 = (((c<<8)+tid)<<3);
      const int4 p0 = *(const int4*)(perm + j0);
      const int4 p1 = *(const int4*)(perm + j0 + 4);
      bf16x8 v;
      v[0]=(__bf16)row[p0.x]; v[1]=(__bf16)row[p0.y];
      v[2]=(__bf16)row[p0.z]; v[3]=(__bf16)row[p0.w];
      v[4]=(__bf16)row[p1.x]; v[5]=(__bf16)row[p1.y];
      v[6]=(__bf16)row[p1.z]; v[7]=(__bf16)row[p1.w];
      *(bf16x8*)(xo + j0) = v;
    }
  } else {
    const int i = (((bid - BB)<<8) + tid)<<3;
    const float4 f0 = ((const float4*)(W+i))[0];
    const float4 f1 = ((const float4*)(W+i))[1];
    bf16x8 v;
    v[0]=(__bf16)f0.x; v[1]=(__bf16)f0.y; v[2]=(__bf16)f0.z; v[3]=(__bf16)f0.w;
    v[4]=(__bf16)f1.x; v[5]=(__bf16)f1.y; v[6]=(__bf16)f1.z; v[7]=(__bf16)f1.w;
    *(bf16x8*)(Wb+i) = v;
  }
}

// ---------------- Pass 2: grouped GEMM, BM=64 x BN=512 (whole group) --------
// Each block owns one (group, 64-row stripe): every xp byte HBM-fetched
// EXACTLY once (structural, L2-independent). 8 waves (1x8), per-wave 64x64
// out -> acc[4][4]=64 VGPR, ~116 total. __launch_bounds__(512,2): VGPR cap
// 128 under CUDA blocks/CU semantics (R7 evidence) or 256 under waves/EU
// semantics -> NO SPILL either way. LDS 72 KB -> 2 blocks/CU.
// Per-XCD B working set = 2 groups x 256 KB = 512 KB (L2-resident).
__global__ void __launch_bounds__(512, 2) gemm_kernel(
    const unsigned short* __restrict__ xp, const unsigned short* __restrict__ Wb,
    const float* __restrict__ bias, float* __restrict__ out)
{
  __shared__ unsigned short lA[64*64];    // 8 KB
  __shared__ unsigned short lB[512*64];   // 64 KB
  const int tid  = threadIdx.x;
  const int lane = tid & 63;
  const int wc   = tid >> 6;        // 0..7  (64 out cols each, 1x8 wave grid)
  const int l15  = lane & 15, lh = lane >> 4;

  // XCD map: 2048 blocks, 256/XCD; xcd owns groups {2xcd, 2xcd+1}.
  const int bid   = blockIdx.x;
  const int xcd   = bid & 7;
  const int local = bid >> 3;                   // 0..255
  const int g     = (xcd << 1) | (local & 1);   // 0..15
  const int by    = local >> 1;                 // 0..127

  const int m0 = by << 6;
  const size_t arow0 = (size_t)m0*CC + (size_t)g*SS;
  const size_t brow0 = (size_t)g*RR*SS;

  f32x4_t acc[4][4];
  #pragma unroll
  for (int i=0;i<4;++i)
    #pragma unroll
    for (int j=0;j<4;++j)
      acc[i][j] = (f32x4_t){0.f,0.f,0.f,0.f};

  #pragma unroll
  for (int t=0;t<4;++t){
    const int kk = t<<6;
    // STAGE A: 64x64 bf16 = 512 chunks (1/thread), swizzled source (T2).
    {
      const int i  = tid;                    // 0..511
      const int r  = i>>3;                   // 0..63
      const int cs = ((i&7) ^ (r&7)) << 3;
      gld_lds16(xp + arow0 + (size_t)r*CC + kk + cs, &lA[i<<3]);
    }
    // STAGE B: 512x64 bf16 = 4096 chunks (8/thread).
    #pragma unroll
    for (int c=0;c<8;++c){
      const int i  = (c<<9) + tid;           // 0..4095
      const int r  = i>>3;                   // 0..511 (n within group)
      const int cs = ((i&7) ^ (r&7)) << 3;
      gld_lds16(Wb + brow0 + (size_t)r*SS + kk + cs, &lB[i<<3]);
    }
    __syncthreads();                         // compiler emits vmcnt(0) drain
    #pragma unroll
    for (int ks=0;ks<2;++ks){
      bf16x8 af[4], bfr[4];
      const int cc = (ks<<2) + lh;           // logical 16B chunk col 0..7
      #pragma unroll
      for (int mi=0;mi<4;++mi){
        const int ar = (mi<<4)+l15;          // 0..63 (full BM per wave)
        af[mi]  = *(const bf16x8*)&lA[ar*64 + ((cc ^ (ar&7))<<3)];
      }
      #pragma unroll
      for (int ni=0;ni<4;++ni){
        const int br = (wc<<6)+(ni<<4)+l15;  // 0..511
        bfr[ni] = *(const bf16x8*)&lB[br*64 + ((cc ^ (br&7))<<3)];
      }
      #pragma unroll
      for (int mi=0;mi<4;++mi)
        #pragma unroll
        for (int ni=0;ni<4;++ni)
          acc[mi][ni] = __builtin_amdgcn_mfma_f32_16x16x32_bf16(af[mi], bfr[ni], acc[mi][ni], 0,0,0);
    }
    __syncthreads();                         // all reads done before next STAGE
  }

  // Epilogue: bias add + store. D layout: col=lane&15, row=(lane>>4)*4+reg.
  #pragma unroll
  for (int ni=0;ni<4;++ni){
    const int col = (g<<9) + (wc<<6) + (ni<<4) + l15;
    const float bv = bias[col];
    #pragma unroll
    for (int mi=0;mi<4;++mi){
      const int rb = m0 + (mi<<4) + (lh<<2);
      float* op = out + (size_t)rb*NN + col;
      #pragma unroll
      for (int r=0;r<4;++r)
        op[(size_t)r*NN] = acc[mi][ni][r] + bv;
    }
  }
}

extern "C" void kernel_launch(void* const* d_in, const int* in_sizes, int n_in,
                              void* d_out, int out_size, void* d_ws, size_t ws_size,
                              hipStream_t stream) {
  const float* x    = (const float*)d_in[0];   // [B, C] f32
  const float* W    = (const float*)d_in[1];   // [G, R, S] f32
  const float* bias = (const float*)d_in[2];   // [G, R] f32
  const int*   perm = (const int*)d_in[3];     // [G, S] int32
  float* out = (float*)d_out;                  // [B, G*R] f32

  unsigned short* xp = (unsigned short*)d_ws;                            // B*C bf16 = 64 MiB
  unsigned short* Wb = (unsigned short*)((char*)d_ws + (size_t)BB*CC*2); // G*R*S bf16 = 4 MiB

  const int wblocks = (GG*RR*SS)/(256*8);      // 1024
  prep_kernel<<<dim3(BB + wblocks), dim3(256), 0, stream>>>(x, perm, W, xp, Wb);
  gemm_kernel<<<dim3(2048), dim3(512), 0, stream>>>(xp, Wb, bias, out);
}

// Round 10
// 126.033 us; speedup vs baseline: 5.1821x; 1.0596x over previous
//
#include <hip/hip_runtime.h>

// Problem constants
#define BB 8192
#define CC 4096
#define GG 16
#define SS 256
#define RR 512
#define NN (GG*RR)   // 8192 output cols

typedef __bf16 bf16x8 __attribute__((ext_vector_type(8)));
typedef float  f32x4_t __attribute__((ext_vector_type(4)));

__device__ __forceinline__ void gld_lds16(const void* g, void* l){
  __builtin_amdgcn_global_load_lds((const __attribute__((address_space(1))) void*)g,
                                   (__attribute__((address_space(3))) void*)l, 16, 0, 0);
}

// ---------------- Pass 1: fused {per-row gather+cast} and {W cast} ----------
// Blocks 0..BB-1: permute+cast one x row (16KB LDS, 8 blk/CU).
// Blocks BB..BB+1023: cast one W chunk. Native bf16 casts (v_cvt_pk_bf16_f32).
__global__ void __launch_bounds__(256) prep_kernel(
    const float* __restrict__ x, const int* __restrict__ perm,
    const float* __restrict__ W,
    unsigned short* __restrict__ xp, unsigned short* __restrict__ Wb)
{
  __shared__ float row[CC];
  const int tid = threadIdx.x;
  const int bid = blockIdx.x;
  if (bid < BB) {
    const size_t b = bid;
    const float4* xr = (const float4*)(x + b*CC);
    float4* rr = (float4*)row;
    #pragma unroll
    for (int c=0;c<4;++c) rr[c*256+tid] = xr[c*256+tid];
    __syncthreads();
    unsigned short* xo = xp + b*CC;
    #pragma unroll
    for (int c=0;c<2;++c){
      const int j0 = (((c<<8)+tid)<<3);
      const int4 p0 = *(const int4*)(perm + j0);
      const int4 p1 = *(const int4*)(perm + j0 + 4);
      bf16x8 v;
      v[0]=(__bf16)row[p0.x]; v[1]=(__bf16)row[p0.y];
      v[2]=(__bf16)row[p0.z]; v[3]=(__bf16)row[p0.w];
      v[4]=(__bf16)row[p1.x]; v[5]=(__bf16)row[p1.y];
      v[6]=(__bf16)row[p1.z]; v[7]=(__bf16)row[p1.w];
      *(bf16x8*)(xo + j0) = v;
    }
  } else {
    const int i = (((bid - BB)<<8) + tid)<<3;
    const float4 f0 = ((const float4*)(W+i))[0];
    const float4 f1 = ((const float4*)(W+i))[1];
    bf16x8 v;
    v[0]=(__bf16)f0.x; v[1]=(__bf16)f0.y; v[2]=(__bf16)f0.z; v[3]=(__bf16)f0.w;
    v[4]=(__bf16)f1.x; v[5]=(__bf16)f1.y; v[6]=(__bf16)f1.z; v[7]=(__bf16)f1.w;
    *(bf16x8*)(Wb+i) = v;
  }
}

// ---------------- Pass 2: grouped GEMM, 128x128 tile, BK=32 x 8 steps -------
// R5 geometry (4 waves 2x2, 3 blocks/CU) + 2-deep dbuf with counted vmcnt:
// the per-thread load queue (4 loads/stage) never drains below 4 until the
// final step -> continuous HBM request stream (fixes the per-step vmcnt(0)
// burstiness). LDS 2x16KB = 32 KB (same footprint as R5). Swizzle for 64B
// rows: chunk ^= (r>>1)&3 -> row-pairs spread, 2-way bank alias = free.
__global__ void __launch_bounds__(256, 3) gemm_kernel(
    const unsigned short* __restrict__ xp, const unsigned short* __restrict__ Wb,
    const float* __restrict__ bias, float* __restrict__ out)
{
  __shared__ unsigned short lA[2][128*32];   // 2 x 8 KB
  __shared__ unsigned short lB[2][128*32];   // 2 x 8 KB
  const int tid  = threadIdx.x;
  const int lane = tid & 63;
  const int w    = tid >> 6;
  const int wr   = w >> 1;          // 0..1  (64 out rows)
  const int wc   = w & 1;           // 0..1  (64 out cols)
  const int l15  = lane & 15, lh = lane >> 4;

  // XCD-aware block mapping: nwg=4096, 512 per XCD, bx-octet per XCD
  // (the 4 n-tiles sharing an A-slice are co-scheduled on one XCD -> L2 hit).
  const int bid   = blockIdx.x;
  const int xcd   = bid & 7;
  const int local = bid >> 3;                   // 0..511
  const int bx    = (xcd << 3) + (local & 7);   // 8 n-tiles = 2 groups per XCD
  const int by    = local >> 3;                 // 0..63

  const int m0 = by << 7;
  const int n0 = bx << 7;
  const int g  = bx >> 2;
  const size_t arow0 = (size_t)m0*CC + (size_t)g*SS;
  const size_t brow0 = (size_t)n0*SS;

  f32x4_t acc[4][4];
  #pragma unroll
  for (int i=0;i<4;++i)
    #pragma unroll
    for (int j=0;j<4;++j)
      acc[i][j] = (f32x4_t){0.f,0.f,0.f,0.f};

  // One stage: A 128x32 + B 128x32 bf16 = 512+512 chunks, 2+2 per thread.
  auto STAGE = [&](int kk, int buf){
    #pragma unroll
    for (int c=0;c<2;++c){
      const int i  = (c<<8) + tid;               // 0..511
      const int r  = i>>2;                       // row 0..127 (4 chunks/row)
      const int cs = ((i&3) ^ ((r>>1)&3)) << 3;  // swizzled source bf16 col
      gld_lds16(xp + arow0 + (size_t)r*CC + kk + cs, &lA[buf][i<<3]);
    }
    #pragma unroll
    for (int c=0;c<2;++c){
      const int i  = (c<<8) + tid;
      const int r  = i>>2;
      const int cs = ((i&3) ^ ((r>>1)&3)) << 3;
      gld_lds16(Wb + brow0 + (size_t)r*SS + kk + cs, &lB[buf][i<<3]);
    }
  };

  auto COMPUTE = [&](int buf){
    bf16x8 af[4], bfr[4];
    #pragma unroll
    for (int mi=0;mi<4;++mi){
      const int ar = (wr<<6)+(mi<<4)+l15;
      af[mi]  = *(const bf16x8*)&lA[buf][ar*32 + ((lh ^ ((ar>>1)&3))<<3)];
    }
    #pragma unroll
    for (int ni=0;ni<4;++ni){
      const int br = (wc<<6)+(ni<<4)+l15;
      bfr[ni] = *(const bf16x8*)&lB[buf][br*32 + ((lh ^ ((br>>1)&3))<<3)];
    }
    #pragma unroll
    for (int mi=0;mi<4;++mi)
      #pragma unroll
      for (int ni=0;ni<4;++ni)
        acc[mi][ni] = __builtin_amdgcn_mfma_f32_16x16x32_bf16(af[mi], bfr[ni], acc[mi][ni], 0,0,0);
  };

  // Prologue: 2 stages in flight (8 loads/thread outstanding).
  STAGE(0, 0);
  STAGE(32, 1);
  #pragma unroll
  for (int t=0;t<8;++t){
    if (t<7) asm volatile("s_waitcnt vmcnt(4)" ::: "memory");
    else     asm volatile("s_waitcnt vmcnt(0)" ::: "memory");
    __builtin_amdgcn_s_barrier();     // buf[t&1] fully landed (all waves)
    COMPUTE(t&1);
    __builtin_amdgcn_s_barrier();     // all waves done reading buf[t&1]
    if (t<6) STAGE((t+2)<<5, t&1);    // refill queue immediately
  }

  // Epilogue: bias add + store. D layout: col=lane&15, row=(lane>>4)*4+reg.
  #pragma unroll
  for (int ni=0;ni<4;++ni){
    const int col = n0 + (wc<<6) + (ni<<4) + l15;
    const float bv = bias[col];
    #pragma unroll
    for (int mi=0;mi<4;++mi){
      const int rb = m0 + (wr<<6) + (mi<<4) + (lh<<2);
      float* op = out + (size_t)rb*NN + col;
      #pragma unroll
      for (int r=0;r<4;++r)
        op[(size_t)r*NN] = acc[mi][ni][r] + bv;
    }
  }
}

extern "C" void kernel_launch(void* const* d_in, const int* in_sizes, int n_in,
                              void* d_out, int out_size, void* d_ws, size_t ws_size,
                              hipStream_t stream) {
  const float* x    = (const float*)d_in[0];   // [B, C] f32
  const float* W    = (const float*)d_in[1];   // [G, R, S] f32
  const float* bias = (const float*)d_in[2];   // [G, R] f32
  const int*   perm = (const int*)d_in[3];     // [G, S] int32
  float* out = (float*)d_out;                  // [B, G*R] f32

  unsigned short* xp = (unsigned short*)d_ws;                            // B*C bf16 = 64 MiB
  unsigned short* Wb = (unsigned short*)((char*)d_ws + (size_t)BB*CC*2); // G*R*S bf16 = 4 MiB

  const int wblocks = (GG*RR*SS)/(256*8);      // 1024
  prep_kernel<<<dim3(BB + wblocks), dim3(256), 0, stream>>>(x, perm, W, xp, Wb);
  gemm_kernel<<<dim3(4096), dim3(256), 0, stream>>>(xp, Wb, bias, out);
}